// Round 1
// baseline (136.993 us; speedup 1.0000x reference)
//
#include <hip/hip_runtime.h>

// Problem constants (from reference)
#define BS 2
#define NF 16
#define CH 32
#define HH 128
#define WW 128
#define HW (HH * WW)          // 16384
#define NM 8                  // NUM_MASKS
#define NK 3                  // NUM_CLASSES
#define MID (NF / 2)          // 8
#define CHUNK 1024            // spatial positions per pool block

// ---------------------------------------------------------------------------
// Kernel 1: masks[b,m,hw] = sum_c dec[b,MID,c,hw] * seg_w[m,c] + seg_b[m]
// Grid: 128 blocks (2 b x 64 chunks of 256 px), 256 threads, 1 px/thread.
// ---------------------------------------------------------------------------
__global__ __launch_bounds__(256) void masks_kernel(
    const float* __restrict__ dec, const float* __restrict__ seg_w,
    const float* __restrict__ seg_b, float* __restrict__ masks_out) {
  __shared__ float w_sh[NM * CH];   // 256 floats
  int tid = threadIdx.x;
  w_sh[tid] = seg_w[tid];
  __syncthreads();

  int bid = blockIdx.x;             // 0..127
  int b = bid >> 6;
  int p = ((bid & 63) << 8) + tid;  // pixel in [0, HW)

  const float* src = dec + (size_t)(b * NF + MID) * CH * HW + p;

  float out[NM];
#pragma unroll
  for (int m = 0; m < NM; ++m) out[m] = seg_b[m];
#pragma unroll
  for (int c = 0; c < CH; ++c) {
    float x = src[c * HW];          // coalesced across lanes (p contiguous)
#pragma unroll
    for (int m = 0; m < NM; ++m) out[m] += x * w_sh[m * CH + c];
  }

  float* dst = masks_out + (size_t)b * NM * HW + p;
#pragma unroll
  for (int m = 0; m < NM; ++m) dst[m * HW] = out[m];
}

// ---------------------------------------------------------------------------
// Kernel 2: acc_ws[b,m,c] += sum_f sum_hw dec[b,f,c,hw] * masks[b,m,hw]
// Grid: 512 blocks = (b, f, chunk of 1024 px), 256 threads.
// Thread handles channels c_lo = tid>>4 and c_lo+16; spatial lanes s = tid&15.
// Masks chunk staged in LDS (8 x 1024 f32 = 32 KB).
// ---------------------------------------------------------------------------
__global__ __launch_bounds__(256) void pool_kernel(
    const float* __restrict__ dec, const float* __restrict__ masks,
    float* __restrict__ acc_ws) {
  __shared__ float lds_mask[NM][CHUNK];

  int tid = threadIdx.x;
  int bid = blockIdx.x;             // 0..511
  int b = bid >> 8;
  int rest = bid & 255;
  int f = rest >> 4;
  int chunk = rest & 15;
  int cs = chunk * CHUNK;

  // Stage mask chunk: row m=i per iteration, 256 float4 = full 1024-row.
  const float* mbase = masks + (size_t)b * NM * HW + cs;
#pragma unroll
  for (int i = 0; i < NM; ++i) {
    float4 v = *(const float4*)(mbase + (size_t)i * HW + tid * 4);
    *(float4*)&lds_mask[i][tid * 4] = v;
  }
  __syncthreads();

  int c_lo = tid >> 4;              // 0..15
  int s = tid & 15;                 // 0..15

  const float4* a0 =
      (const float4*)(dec + ((size_t)((b * NF + f) * CH + c_lo)) * HW + cs);
  const float4* a1 =
      (const float4*)(dec + ((size_t)((b * NF + f) * CH + c_lo + 16)) * HW + cs);

  float acc0[NM], acc1[NM];
#pragma unroll
  for (int m = 0; m < NM; ++m) { acc0[m] = 0.f; acc1[m] = 0.f; }

#pragma unroll 4
  for (int k = 0; k < CHUNK / 64; ++k) {   // 16 iterations
    int p4 = s + 16 * k;
    float4 x0 = a0[p4];
    float4 x1 = a1[p4];
#pragma unroll
    for (int m = 0; m < NM; ++m) {
      float4 w = *(const float4*)&lds_mask[m][p4 * 4];
      acc0[m] += x0.x * w.x + x0.y * w.y + x0.z * w.z + x0.w * w.w;
      acc1[m] += x1.x * w.x + x1.y * w.y + x1.z * w.z + x1.w * w.w;
    }
  }

  // Reduce across the 16 spatial lanes (consecutive within the wave).
#pragma unroll
  for (int off = 8; off >= 1; off >>= 1) {
#pragma unroll
    for (int m = 0; m < NM; ++m) {
      acc0[m] += __shfl_down(acc0[m], off, 16);
      acc1[m] += __shfl_down(acc1[m], off, 16);
    }
  }

  if (s == 0) {
#pragma unroll
    for (int m = 0; m < NM; ++m) {
      atomicAdd(&acc_ws[(b * NM + m) * CH + c_lo], acc0[m]);
      atomicAdd(&acc_ws[(b * NM + m) * CH + c_lo + 16], acc1[m]);
    }
  }
}

// ---------------------------------------------------------------------------
// Kernel 3: logits[b, m*NK+k] = (acc_ws[b,m,:]/NF) . logits_w[k,:] + logits_b[k]
// ---------------------------------------------------------------------------
__global__ void head_kernel(const float* __restrict__ acc_ws,
                            const float* __restrict__ lw,
                            const float* __restrict__ lb,
                            float* __restrict__ out) {
  int t = threadIdx.x;
  if (t < BS * NM * NK) {
    int b = t / (NM * NK);
    int r = t % (NM * NK);
    int m = r / NK;
    int k = r % NK;
    float ssum = 0.f;
#pragma unroll
    for (int c = 0; c < CH; ++c)
      ssum += acc_ws[(b * NM + m) * CH + c] * lw[k * CH + c];
    out[t] = ssum * (1.0f / NF) + lb[k];
  }
}

extern "C" void kernel_launch(void* const* d_in, const int* in_sizes, int n_in,
                              void* d_out, int out_size, void* d_ws,
                              size_t ws_size, hipStream_t stream) {
  const float* dec = (const float*)d_in[0];     // (2,16,32,128,128)
  const float* seg_w = (const float*)d_in[1];   // (8,32)
  const float* seg_b = (const float*)d_in[2];   // (8,)
  const float* lw = (const float*)d_in[3];      // (3,32)
  const float* lb = (const float*)d_in[4];      // (3,)

  float* out = (float*)d_out;
  float* logits_out = out;                 // 48 floats
  float* masks_out = out + BS * NM * NK;   // 262144 floats, 192B offset (16B-aligned)
  float* acc_ws = (float*)d_ws;            // 512 floats

  hipMemsetAsync(d_ws, 0, BS * NM * CH * sizeof(float), stream);

  masks_kernel<<<BS * 64, 256, 0, stream>>>(dec, seg_w, seg_b, masks_out);
  pool_kernel<<<BS * NF * (HW / CHUNK), 256, 0, stream>>>(dec, masks_out, acc_ws);
  head_kernel<<<1, 64, 0, stream>>>(acc_ws, lw, lb, logits_out);
}